// Round 3
// baseline (190.592 us; speedup 1.0000x reference)
//
#include <hip/hip_runtime.h>
#include <hip/hip_bf16.h>
#include <cstddef>

// ---------------------------------------------------------------------------
// 2-layer GCN: h1 = x@W1; hmid = relu(Agg(h1) + b1); h2 = hmid@W2;
// out = Agg(h2) + b2.  Agg = sym-normalized scatter-add with self-loops.
// R15: coalesced csr preload + shfl broadcast (kill offs->csr->gather chain).
// R16 (this):
//  (a) h1 stored UNSCALED -> gemm1 no longer depends on scan; fused into
//      count_kernel's grid (fills count's atomic-latency idle issue slots).
//      Per-edge weight dinv[src] comes from csrw[] written by fill (coalesced
//      preload + shfl, no new random gathers); self term x dinv[d]; the
//      weight multiply already existed for dead-slot zeroing -> free.
//  (b) aggmm: 4 nodes' edge streams INTERLEAVED in one loop (granule 4,
//      wave-uniform skip) -> 4x MLP, dead-slot waste 36% -> 16%.
//  (c) aggout: same restructure, 4 nodes/wave.
//  (d) init kernel (replaces memset): deg zero + W-frag + lb zero.
// ---------------------------------------------------------------------------

typedef __attribute__((ext_vector_type(8))) short short8;
typedef __attribute__((ext_vector_type(4))) float f32x4;
typedef unsigned long long u64;

__device__ inline unsigned short f2bf(float f) {
    __hip_bfloat16 b = __float2bfloat16(f);
    return *reinterpret_cast<unsigned short*>(&b);
}
__device__ inline float bf2f_lo(unsigned int u) {
    unsigned int v = u << 16;
    return *reinterpret_cast<float*>(&v);
}
__device__ inline float bf2f_hi(unsigned int u) {
    unsigned int v = u & 0xffff0000u;
    return *reinterpret_cast<float*>(&v);
}
__device__ inline u64 ld_acq64(u64* p) {
    return __hip_atomic_load(p, __ATOMIC_ACQUIRE, __HIP_MEMORY_SCOPE_AGENT);
}
__device__ inline void st_rel64(u64* p, u64 v) {
    __hip_atomic_store(p, v, __ATOMIC_RELEASE, __HIP_MEMORY_SCOPE_AGENT);
}

// ---------------------------------------------------------------------------
// init: blocks [0,ZB) zero deg (int4); blocks [ZB,ZB+12) convert W1/W2 to
// MFMA-B fragment order + zero lb.
// ---------------------------------------------------------------------------
__global__ __launch_bounds__(256) void init_kernel(int* __restrict__ deg, int N,
                                                   const float* __restrict__ W1,
                                                   const float* __restrict__ W2,
                                                   unsigned short* __restrict__ W1f,
                                                   unsigned short* __restrict__ W2f,
                                                   u64* __restrict__ lb, int ZB) {
    int b = blockIdx.x;
    int tid = threadIdx.x;
    if (b < ZB) {
        int i = (b * 256 + tid) * 4;
        if (i + 3 < N) *(int4*)(deg + i) = make_int4(0, 0, 0, 0);
        else for (; i < N; i++) deg[i] = 0;
        return;
    }
    int idx = (b - ZB) * 256 + tid;
    if (idx < 64) lb[idx] = 0;
    if (idx < 3072) {
        const float* W;
        unsigned short* Wf;
        int n, oct, Nc;
        if (idx < 2048) { W = W1; Wf = W1f; Nc = 128; n = idx >> 4; oct = idx & 15; }
        else { W = W2; Wf = W2f; Nc = 64; int i2 = idx - 2048; n = i2 >> 4; oct = i2 & 15; }
        int k0 = oct * 8;
        int ks = k0 >> 5, quad = (k0 >> 3) & 3, ntg = n >> 4;
        short8 v;
        #pragma unroll
        for (int j = 0; j < 8; j++) v[j] = (short)f2bf(W[(k0 + j) * Nc + n]);
        int off = (((ntg * 4 + ks) * 64) + (n & 15) + 16 * quad) * 8;
        *(short8*)(Wf + off) = v;
    }
}

// ---------------------------------------------------------------------------
// countgemm: blocks [0, CB) count 4 edges/thread (int4 load), capturing
// within-dst rank from atomicAdd return. Blocks [CB, CB+GB): gemm1
// h1 = bf16(x @ W1) UNSCALED (independent of edges -> hides atomic latency).
// ---------------------------------------------------------------------------
__global__ __launch_bounds__(256) void countgemm_kernel(
    const int* __restrict__ dst, int E,
    int* __restrict__ deg, unsigned short* __restrict__ rank,
    const float* __restrict__ x, const unsigned short* __restrict__ W1f,
    unsigned short* __restrict__ h1, int N, int CB) {

    int b = blockIdx.x;
    int tid = threadIdx.x;

    __shared__ unsigned short As[64 * 128];  // 16 KB (gemm blocks only)

    if (b < CB) {
        int i = (b * 256 + tid) * 4;
        if (i + 3 < E) {
            int4 d = *(const int4*)(dst + i);
            unsigned short r0 = (unsigned short)atomicAdd(&deg[d.x], 1);
            unsigned short r1 = (unsigned short)atomicAdd(&deg[d.y], 1);
            unsigned short r2 = (unsigned short)atomicAdd(&deg[d.z], 1);
            unsigned short r3 = (unsigned short)atomicAdd(&deg[d.w], 1);
            *(ushort4*)(rank + i) = make_ushort4(r0, r1, r2, r3);
        } else {
            for (; i < E; i++) rank[i] = (unsigned short)atomicAdd(&deg[dst[i]], 1);
        }
        return;
    }

    // ---------------- gemm1: h1 = bf16(x @ W1) ----------------
    constexpr int K = 128, BN = 128;
    int lane = tid & 63;
    int w = tid >> 6;
    int row0 = (b - CB) * 64;

    short8 bfr[2][4];
    #pragma unroll
    for (int nl = 0; nl < 2; nl++)
        #pragma unroll
        for (int ks = 0; ks < 4; ks++)
            bfr[nl][ks] = *(const short8*)(W1f + ((((w * 2 + nl) * 4 + ks) * 64) + lane) * 8);

    #pragma unroll
    for (int it = 0; it < 8; it++) {
        int idx = it * 256 + tid;
        int row = idx >> 5, kq = idx & 31;
        int k0 = kq * 4;
        int ks = k0 >> 5, quad = (k0 >> 3) & 3, j0 = k0 & 7, mt = row >> 4;
        ushort4 o = make_ushort4(0, 0, 0, 0);
        int gr = row0 + row;
        if (gr < N) {
            float4 a = *(const float4*)(x + (size_t)gr * K + k0);
            o.x = f2bf(a.x); o.y = f2bf(a.y); o.z = f2bf(a.z); o.w = f2bf(a.w);
        }
        int off = (((mt * 4 + ks) * 64) + (row & 15) + 16 * quad) * 8 + j0;
        *(ushort4*)(As + off) = o;
    }
    __syncthreads();

    f32x4 acc[4][2];
    #pragma unroll
    for (int mt = 0; mt < 4; mt++)
        #pragma unroll
        for (int nl = 0; nl < 2; nl++) acc[mt][nl] = (f32x4){0.f, 0.f, 0.f, 0.f};

    #pragma unroll
    for (int ks = 0; ks < 4; ks++) {
        short8 af[4];
        #pragma unroll
        for (int mt = 0; mt < 4; mt++)
            af[mt] = *(const short8*)(As + (((mt * 4 + ks) * 64) + lane) * 8);
        #pragma unroll
        for (int mt = 0; mt < 4; mt++)
            #pragma unroll
            for (int nl = 0; nl < 2; nl++)
                acc[mt][nl] = __builtin_amdgcn_mfma_f32_16x16x32_bf16(
                    af[mt], bfr[nl][ks], acc[mt][nl], 0, 0, 0);
    }

    int col16 = lane & 15;
    int rowq = lane >> 4;
    #pragma unroll
    for (int mt = 0; mt < 4; mt++) {
        #pragma unroll
        for (int nl = 0; nl < 2; nl++) {
            int gc = (w * 2 + nl) * 16 + col16;
            #pragma unroll
            for (int r = 0; r < 4; r++) {
                int lr = mt * 16 + rowq * 4 + r;
                int gr = row0 + lr;
                if (gr < N) h1[(size_t)gr * BN + gc] = f2bf(acc[mt][nl][r]);
            }
        }
    }
}

// ---------------------------------------------------------------------------
// scan_lb: one-pass exclusive scan of deg via wave-parallel decoupled
// lookback. Writes offs, dinv.
// ---------------------------------------------------------------------------
__global__ __launch_bounds__(256) void scan_lb_kernel(const int* __restrict__ deg, int N,
                                                      u64* __restrict__ lb,
                                                      int* __restrict__ offs,
                                                      float* __restrict__ dinv) {
    __shared__ int ws[4];
    __shared__ int s_prefix;
    int tid = threadIdx.x;
    int sb = blockIdx.x;
    int SB = gridDim.x;
    int lane = tid & 63;
    int wv = tid >> 6;

    int i = sb * 1024 + tid * 4;
    int v0 = (i + 0 < N) ? deg[i + 0] : 0;
    int v1 = (i + 1 < N) ? deg[i + 1] : 0;
    int v2 = (i + 2 < N) ? deg[i + 2] : 0;
    int v3 = (i + 3 < N) ? deg[i + 3] : 0;
    int tsum = v0 + v1 + v2 + v3;
    int xs = tsum;
    #pragma unroll
    for (int off = 1; off < 64; off <<= 1) {
        int y = __shfl_up(xs, off, 64);
        if (lane >= off) xs += y;
    }
    if (lane == 63) ws[wv] = xs;
    __syncthreads();
    int wprefix = 0;
    #pragma unroll
    for (int w2 = 0; w2 < 4; w2++) wprefix += (w2 < wv) ? ws[w2] : 0;
    int chunk_total = ws[0] + ws[1] + ws[2] + ws[3];

    if (wv == 0) {
        if (lane == 0)
            st_rel64(&lb[sb], ((u64)(unsigned)chunk_total << 2) | 1ull);
        int contrib = 0;
        if (sb > 0) {
            int pred = sb - 1 - lane;  // lane 0 = nearest predecessor
            for (;;) {
                u64 v = (pred >= 0) ? ld_acq64(&lb[pred]) : 2ull;  // sentinel: flag 2, val 0
                int flag = (int)(v & 3);
                u64 ball2 = __ballot(flag == 2);
                u64 ball0 = __ballot(flag == 0);
                if (ball2 != 0) {
                    int L = __ffsll(ball2) - 1;
                    if ((ball0 & ((1ull << L) - 1)) == 0) {
                        contrib = (lane <= L) ? (int)(unsigned)(v >> 2) : 0;
                        break;
                    }
                }
                __builtin_amdgcn_s_sleep(1);
            }
            #pragma unroll
            for (int off = 32; off >= 1; off >>= 1)
                contrib += __shfl_xor(contrib, off, 64);
        }
        if (lane == 0) {
            st_rel64(&lb[sb], ((u64)(unsigned)(contrib + chunk_total) << 2) | 2ull);
            s_prefix = contrib;
        }
    }
    __syncthreads();

    int carry = s_prefix;
    int e0 = carry + wprefix + xs - tsum;
    int e1 = e0 + v0, e2 = e1 + v1, e3 = e2 + v2;
    if (i + 0 < N) { offs[i + 0] = e0; dinv[i + 0] = rsqrtf((float)(v0 + 1)); }
    if (i + 1 < N) { offs[i + 1] = e1; dinv[i + 1] = rsqrtf((float)(v1 + 1)); }
    if (i + 2 < N) { offs[i + 2] = e2; dinv[i + 2] = rsqrtf((float)(v2 + 1)); }
    if (i + 3 < N) { offs[i + 3] = e3; dinv[i + 3] = rsqrtf((float)(v3 + 1)); }
    if (sb == SB - 1 && tid == 0) offs[N] = carry + chunk_total;
}

// ---------------------------------------------------------------------------
// fill: CSR fill (no atomics: pos = offs[d] + rank[e]); also writes
// csrw[pos] = dinv[src] so aggmm gets per-edge weights coalesced.
// ---------------------------------------------------------------------------
__global__ __launch_bounds__(256) void fill_kernel(
    const int* __restrict__ src, const int* __restrict__ dst, int E,
    const int* __restrict__ offs, const unsigned short* __restrict__ rank,
    const float* __restrict__ dinv, int* __restrict__ csr,
    float* __restrict__ csrw) {
    int i = blockIdx.x * 256 + threadIdx.x;
    if (i < E) {
        int s = src[i];
        int d = dst[i];
        int pos = offs[d] + (int)rank[i];
        csr[pos] = s;
        csrw[pos] = dinv[s];
    }
}

// ---------------------------------------------------------------------------
// aggmm: fused Agg(layer1) + bias + ReLU + GEMM2, h2 epilogue-scaled by dinv.
// hmid[d] = relu(dinv[d]*(dinv[d]*h1[d] + sum_e dinv[s]*h1[s]) + b1)
// Block = 4 waves = 16 nodes; 32 lanes/edge (uint2). R16: the wave's 4 nodes'
// edge streams interleaved (granule 4 = 2 slots x unroll 2, wave-uniform
// skip) -> 4x MLP, ~16% dead-slot waste. Weights preloaded from csrw.
// ---------------------------------------------------------------------------
__global__ __launch_bounds__(256) void aggmm_kernel(const unsigned short* __restrict__ h1,
                                                    const int* __restrict__ offs,
                                                    const int* __restrict__ csr,
                                                    const float* __restrict__ csrw,
                                                    const float* __restrict__ dinv,
                                                    const float* __restrict__ b1,
                                                    const unsigned short* __restrict__ W2f,
                                                    unsigned short* __restrict__ h2,
                                                    int n) {
    __shared__ unsigned short As[4 * 64 * 8];  // 4 KB, one 16x128 A-tile

    int tid = threadIdx.x;
    int t = tid & 63;
    int w = tid >> 6;
    int p = t >> 5;      // edge slot (0/1)
    int t5 = t & 31;     // feature quad index (4 bf16)
    int nodebase = blockIdx.x * 16;
    int node0 = nodebase + w * 4;

    // --- preload offs[node0..node0+4], csr + csrw blocks, dinv per node ---
    int ov = offs[min(node0 + min(t, 4), n)];
    int e0a[4], dega[4], nba[4], cidx[4];
    float cwv[4], dia[4];
    #pragma unroll
    for (int i = 0; i < 4; i++) {
        e0a[i] = __shfl(ov, i, 64);
        dega[i] = __shfl(ov, i + 1, 64) - e0a[i];
        nba[i] = min(dega[i], 64);
        int ce = e0a[i] + min(t, max(dega[i] - 1, 0));
        bool has = dega[i] > 0;
        cidx[i] = has ? csr[ce] : 0;
        cwv[i] = has ? csrw[ce] : 0.f;
        int node = node0 + i;
        dia[i] = (node < n) ? dinv[node] : 0.f;
    }

    short8 bw[4];
    #pragma unroll
    for (int ks = 0; ks < 4; ks++)
        bw[ks] = *(const short8*)(W2f + (((w * 4 + ks) * 64) + t) * 8);

    float4 bias = *(const float4*)(b1 + t5 * 4);

    float a[4][4];
    #pragma unroll
    for (int i = 0; i < 4; i++)
        #pragma unroll
        for (int k = 0; k < 4; k++) a[i][k] = 0.f;

    // self terms (weight dinv[d], p==0 slot only)
    #pragma unroll
    for (int i = 0; i < 4; i++) {
        int node = node0 + i;
        if (node < n && p == 0) {
            uint2 su = *(const uint2*)(h1 + (size_t)node * 128 + t5 * 4);
            a[i][0] = bf2f_lo(su.x) * dia[i]; a[i][1] = bf2f_hi(su.x) * dia[i];
            a[i][2] = bf2f_lo(su.y) * dia[i]; a[i][3] = bf2f_hi(su.y) * dia[i];
        }
    }

    // interleaved main loop: granule 4 per node per iteration
    int itTop = (max(max(nba[0], nba[1]), max(nba[2], nba[3])) + 3) >> 2;
    for (int it = 0; it < itTop; ++it) {
        int base = it * 4;
        #pragma unroll
        for (int i = 0; i < 4; i++) {
            if (base < nba[i]) {
                #pragma unroll
                for (int j = 0; j < 2; j++) {
                    int ee = base + j * 2 + p;
                    int ec = min(ee, nba[i] - 1);
                    int s = __shfl(cidx[i], ec, 64);
                    float wv = __shfl(cwv[i], ec, 64);
                    wv = (ee < nba[i]) ? wv : 0.f;
                    uint2 hu = *(const uint2*)(h1 + (size_t)s * 128 + t5 * 4);
                    a[i][0] += bf2f_lo(hu.x) * wv; a[i][1] += bf2f_hi(hu.x) * wv;
                    a[i][2] += bf2f_lo(hu.y) * wv; a[i][3] += bf2f_hi(hu.y) * wv;
                }
            }
        }
    }
    // rare tail: deg > 64 (weights gathered directly)
    #pragma unroll
    for (int i = 0; i < 4; i++) {
        int e1 = e0a[i] + dega[i];
        for (int eb = e0a[i] + 64; eb < e1; eb += 2) {
            int ee = eb + p;
            int ec = min(ee, e1 - 1);
            int s = csr[ec];
            float wv = (ee < e1) ? dinv[s] : 0.f;
            uint2 hu = *(const uint2*)(h1 + (size_t)s * 128 + t5 * 4);
            a[i][0] += bf2f_lo(hu.x) * wv; a[i][1] += bf2f_hi(hu.x) * wv;
            a[i][2] += bf2f_lo(hu.y) * wv; a[i][3] += bf2f_hi(hu.y) * wv;
        }
    }

    // reduce slots, bias+relu, stage into As
    #pragma unroll
    for (int i = 0; i < 4; i++) {
        float a0 = a[i][0], a1 = a[i][1], a2 = a[i][2], a3 = a[i][3];
        a0 += __shfl_xor(a0, 32, 64);
        a1 += __shfl_xor(a1, 32, 64);
        a2 += __shfl_xor(a2, 32, 64);
        a3 += __shfl_xor(a3, 32, 64);
        if (p == 0) {
            a0 = fmaxf(a0 * dia[i] + bias.x, 0.f);
            a1 = fmaxf(a1 * dia[i] + bias.y, 0.f);
            a2 = fmaxf(a2 * dia[i] + bias.z, 0.f);
            a3 = fmaxf(a3 * dia[i] + bias.w, 0.f);
            int row16 = w * 4 + i;
            int k0 = t5 * 4;
            int ks = k0 >> 5, quad = (k0 >> 3) & 3, j0 = k0 & 7;
            ushort4 pk4 = make_ushort4(f2bf(a0), f2bf(a1), f2bf(a2), f2bf(a3));
            *(ushort4*)(As + ((ks * 64) + row16 + 16 * quad) * 8 + j0) = pk4;
        }
    }
    __syncthreads();

    f32x4 acc = (f32x4){0.f, 0.f, 0.f, 0.f};
    #pragma unroll
    for (int ks = 0; ks < 4; ks++) {
        short8 af = *(const short8*)(As + ((ks * 64) + t) * 8);
        acc = __builtin_amdgcn_mfma_f32_16x16x32_bf16(af, bw[ks], acc, 0, 0, 0);
    }

    int col = w * 16 + (t & 15);
    int rowq = t >> 4;
    #pragma unroll
    for (int r = 0; r < 4; r++) {
        int gr = nodebase + rowq * 4 + r;
        if (gr < n) h2[(size_t)gr * 64 + col] = f2bf(acc[r] * dinv[gr]);
    }
}

// ---------------------------------------------------------------------------
// aggout: out[d] = dinv[d]*(h2'[d] + sum_e h2'[src]) + b2, fp32 out.
// R16: 4 nodes/wave (was 1), 16 lanes/edge, 4 slots, granule 4, interleaved
// with wave-uniform skip. Coalesced csr preload + shfl broadcast.
// ---------------------------------------------------------------------------
__global__ __launch_bounds__(256) void aggout_kernel(const unsigned short* __restrict__ h2,
                                                     const int* __restrict__ offs,
                                                     const int* __restrict__ csr,
                                                     const float* __restrict__ dinv,
                                                     const float* __restrict__ b2,
                                                     float* __restrict__ out, int n) {
    int tid = threadIdx.x;
    int t = tid & 63;
    int w = tid >> 6;
    int p = t >> 4;      // edge slot (0..3)
    int t4 = t & 15;     // feature quad index
    int node0 = blockIdx.x * 16 + w * 4;

    int ov = offs[min(node0 + min(t, 4), n)];
    int e0a[4], dega[4], nba[4], cidx[4];
    float dia[4];
    #pragma unroll
    for (int i = 0; i < 4; i++) {
        e0a[i] = __shfl(ov, i, 64);
        dega[i] = __shfl(ov, i + 1, 64) - e0a[i];
        nba[i] = min(dega[i], 64);
        int ce = e0a[i] + min(t, max(dega[i] - 1, 0));
        cidx[i] = (dega[i] > 0) ? csr[ce] : 0;
        int node = node0 + i;
        dia[i] = (node < n) ? dinv[node] : 0.f;
    }

    float a[4][4];
    #pragma unroll
    for (int i = 0; i < 4; i++)
        #pragma unroll
        for (int k = 0; k < 4; k++) a[i][k] = 0.f;

    // self terms (p==0 slot)
    #pragma unroll
    for (int i = 0; i < 4; i++) {
        int node = node0 + i;
        if (node < n && p == 0) {
            uint2 su = *(const uint2*)(h2 + (size_t)node * 64 + t4 * 4);
            a[i][0] = bf2f_lo(su.x); a[i][1] = bf2f_hi(su.x);
            a[i][2] = bf2f_lo(su.y); a[i][3] = bf2f_hi(su.y);
        }
    }

    int itTop = (max(max(nba[0], nba[1]), max(nba[2], nba[3])) + 3) >> 2;
    for (int it = 0; it < itTop; ++it) {
        int base = it * 4;
        #pragma unroll
        for (int i = 0; i < 4; i++) {
            if (base < nba[i]) {
                int ee = base + p;
                int ec = min(ee, nba[i] - 1);
                int s = __shfl(cidx[i], ec, 64);
                float wgt = (ee < nba[i]) ? 1.f : 0.f;
                uint2 hu = *(const uint2*)(h2 + (size_t)s * 64 + t4 * 4);
                a[i][0] += bf2f_lo(hu.x) * wgt; a[i][1] += bf2f_hi(hu.x) * wgt;
                a[i][2] += bf2f_lo(hu.y) * wgt; a[i][3] += bf2f_hi(hu.y) * wgt;
            }
        }
    }
    // rare tail: deg > 64
    #pragma unroll
    for (int i = 0; i < 4; i++) {
        int e1 = e0a[i] + dega[i];
        for (int eb = e0a[i] + 64; eb < e1; eb += 4) {
            int ee = eb + p;
            int ec = min(ee, e1 - 1);
            int s = csr[ec];
            float wgt = (ee < e1) ? 1.f : 0.f;
            uint2 hu = *(const uint2*)(h2 + (size_t)s * 64 + t4 * 4);
            a[i][0] += bf2f_lo(hu.x) * wgt; a[i][1] += bf2f_hi(hu.x) * wgt;
            a[i][2] += bf2f_lo(hu.y) * wgt; a[i][3] += bf2f_hi(hu.y) * wgt;
        }
    }

    #pragma unroll
    for (int i = 0; i < 4; i++) {
        float a0 = a[i][0], a1 = a[i][1], a2 = a[i][2], a3 = a[i][3];
        a0 += __shfl_xor(a0, 16, 64); a1 += __shfl_xor(a1, 16, 64);
        a2 += __shfl_xor(a2, 16, 64); a3 += __shfl_xor(a3, 16, 64);
        a0 += __shfl_xor(a0, 32, 64); a1 += __shfl_xor(a1, 32, 64);
        a2 += __shfl_xor(a2, 32, 64); a3 += __shfl_xor(a3, 32, 64);
        int node = node0 + i;
        if (p == 0 && node < n) {
            float4 bb = *(const float4*)(b2 + t4 * 4);
            *(float4*)(out + (size_t)node * 64 + t4 * 4) =
                make_float4(a0 * dia[i] + bb.x, a1 * dia[i] + bb.y,
                            a2 * dia[i] + bb.z, a3 * dia[i] + bb.w);
        }
    }
}

extern "C" void kernel_launch(void* const* d_in, const int* in_sizes, int n_in,
                              void* d_out, int out_size, void* d_ws, size_t ws_size,
                              hipStream_t stream) {
    const float* x  = (const float*)d_in[0];
    const int*   ei = (const int*)d_in[1];
    const float* W1 = (const float*)d_in[2];
    const float* b1 = (const float*)d_in[3];
    const float* W2 = (const float*)d_in[4];
    const float* b2 = (const float*)d_in[5];

    const int N = in_sizes[0] / 128;   // 50000
    const int E = in_sizes[1] / 2;     // 500000
    const int* src = ei;
    const int* dst = ei + E;

    char* p = (char*)d_ws;
    auto alloc = [&](size_t bytes) {
        char* r = p;
        p += (bytes + 255) & ~(size_t)255;
        return r;
    };
    int*   degi  = (int*)  alloc((size_t)N * 4);
    float* dinv  = (float*)alloc((size_t)N * 4);
    int*   offs  = (int*)  alloc((size_t)(N + 1) * 4);
    u64*   lb    = (u64*)  alloc((size_t)64 * 8);
    unsigned short* rank = (unsigned short*)alloc((size_t)E * 2);
    int*            csr  = (int*)alloc((size_t)E * 4);
    float*          csrw = (float*)alloc((size_t)E * 4);
    unsigned short* W1f  = (unsigned short*)alloc((size_t)128 * 128 * 2);
    unsigned short* W2f  = (unsigned short*)alloc((size_t)64 * 128 * 2);
    unsigned short* h1   = (unsigned short*)alloc((size_t)N * 128 * 2);
    unsigned short* h2   = (unsigned short*)alloc((size_t)N * 64 * 2);
    float* out = (float*)d_out;

    const int GB = (N + 63) / 64;        // 782
    const int FB = (E + 255) / 256;      // 1954
    const int SB = (N + 1023) / 1024;    // 49
    const int CB = (E / 4 + 255) / 256;  // 489
    const int ZB = (N + 1023) / 1024;    // 49

    init_kernel<<<ZB + 12, 256, 0, stream>>>(degi, N, W1, W2, W1f, W2f, lb, ZB);
    countgemm_kernel<<<CB + GB, 256, 0, stream>>>(dst, E, degi, rank, x, W1f, h1, N, CB);
    scan_lb_kernel<<<SB, 256, 0, stream>>>(degi, N, lb, offs, dinv);
    fill_kernel<<<FB, 256, 0, stream>>>(src, dst, E, offs, rank, dinv, csr, csrw);
    aggmm_kernel<<<(N + 15) / 16, 256, 0, stream>>>(h1, offs, csr, csrw, dinv, b1, W2f, h2, N);
    aggout_kernel<<<(N + 15) / 16, 256, 0, stream>>>(h2, offs, csr, dinv, b2, out, N);
}

// Round 4
// 174.949 us; speedup vs baseline: 1.0894x; 1.0894x over previous
//
#include <hip/hip_runtime.h>
#include <hip/hip_bf16.h>
#include <cstddef>

// ---------------------------------------------------------------------------
// 2-layer GCN: h1 = x@W1; hmid = relu(Agg(h1) + b1); h2 = hmid@W2;
// out = Agg(h2) + b2.  Agg = sym-normalized scatter-add with self-loops.
// R15 (base, 171.2us): coalesced csr preload + shfl broadcast.
// R16: 4-change bundle REGRESSED (190.6). Root cause identified: interleaved
//   gathers wrapped in per-node `if` -> load+use inside each branch body ->
//   compiler emits vmcnt(0) per body -> loads serialized, memory clause dead.
//   (csrw random dinv[src] gather in fill + countgemm reshuffle also suspect.)
// R17 (this): revert to R15 everywhere EXCEPT agg inner loops, which get the
//   interleave done BRANCHLESSLY: all loads issued unconditionally in
//   straight line (clamped shfl index -> dead slots re-read last row = L1
//   hit, weight 0), then all accumulates. aggmm: 8 loads in flight (was 4);
//   aggout: 4 nodes/wave, 8 in flight (was 2). No other changes.
// ---------------------------------------------------------------------------

typedef __attribute__((ext_vector_type(8))) short short8;
typedef __attribute__((ext_vector_type(4))) float f32x4;
typedef unsigned long long u64;

__device__ inline unsigned short f2bf(float f) {
    __hip_bfloat16 b = __float2bfloat16(f);
    return *reinterpret_cast<unsigned short*>(&b);
}
__device__ inline float bf2f_lo(unsigned int u) {
    unsigned int v = u << 16;
    return *reinterpret_cast<float*>(&v);
}
__device__ inline float bf2f_hi(unsigned int u) {
    unsigned int v = u & 0xffff0000u;
    return *reinterpret_cast<float*>(&v);
}
__device__ inline u64 ld_acq64(u64* p) {
    return __hip_atomic_load(p, __ATOMIC_ACQUIRE, __HIP_MEMORY_SCOPE_AGENT);
}
__device__ inline void st_rel64(u64* p, u64 v) {
    __hip_atomic_store(p, v, __ATOMIC_RELEASE, __HIP_MEMORY_SCOPE_AGENT);
}

// ---------------------------------------------------------------------------
// count: blocks [0, CB) count 4 edges/thread (int4 load), capturing
// within-dst rank from atomicAdd return (fill needs no atomics).
// Blocks [CB, CB+12): W1/W2 -> global MFMA-B fragment order + lb zeroing.
// ---------------------------------------------------------------------------
__global__ __launch_bounds__(256) void count_kernel(const int* __restrict__ dst, int E,
                                                    int* __restrict__ deg,
                                                    unsigned short* __restrict__ rank,
                                                    const float* __restrict__ W1,
                                                    const float* __restrict__ W2,
                                                    unsigned short* __restrict__ W1f,
                                                    unsigned short* __restrict__ W2f,
                                                    u64* __restrict__ lb, int CB) {
    int b = blockIdx.x;
    int tid = threadIdx.x;
    if (b >= CB) {
        int idx = (b - CB) * 256 + tid;
        if (idx < 64) lb[idx] = 0;
        if (idx < 3072) {
            const float* W;
            unsigned short* Wf;
            int n, oct, Nc;
            if (idx < 2048) { W = W1; Wf = W1f; Nc = 128; n = idx >> 4; oct = idx & 15; }
            else { W = W2; Wf = W2f; Nc = 64; int i2 = idx - 2048; n = i2 >> 4; oct = i2 & 15; }
            int k0 = oct * 8;
            int ks = k0 >> 5, quad = (k0 >> 3) & 3, ntg = n >> 4;
            short8 v;
            #pragma unroll
            for (int j = 0; j < 8; j++) v[j] = (short)f2bf(W[(k0 + j) * Nc + n]);
            int off = (((ntg * 4 + ks) * 64) + (n & 15) + 16 * quad) * 8;
            *(short8*)(Wf + off) = v;
        }
        return;
    }
    int i = (b * 256 + tid) * 4;
    if (i + 3 < E) {
        int4 d = *(const int4*)(dst + i);
        unsigned short r0 = (unsigned short)atomicAdd(&deg[d.x], 1);
        unsigned short r1 = (unsigned short)atomicAdd(&deg[d.y], 1);
        unsigned short r2 = (unsigned short)atomicAdd(&deg[d.z], 1);
        unsigned short r3 = (unsigned short)atomicAdd(&deg[d.w], 1);
        *(ushort4*)(rank + i) = make_ushort4(r0, r1, r2, r3);
    } else {
        for (; i < E; i++) rank[i] = (unsigned short)atomicAdd(&deg[dst[i]], 1);
    }
}

// ---------------------------------------------------------------------------
// scan_lb: one-pass exclusive scan of deg via wave-parallel decoupled
// lookback. Writes offs, dinv.
// ---------------------------------------------------------------------------
__global__ __launch_bounds__(256) void scan_lb_kernel(const int* __restrict__ deg, int N,
                                                      u64* __restrict__ lb,
                                                      int* __restrict__ offs,
                                                      float* __restrict__ dinv) {
    __shared__ int ws[4];
    __shared__ int s_prefix;
    int tid = threadIdx.x;
    int sb = blockIdx.x;
    int SB = gridDim.x;
    int lane = tid & 63;
    int wv = tid >> 6;

    int i = sb * 1024 + tid * 4;
    int v0 = (i + 0 < N) ? deg[i + 0] : 0;
    int v1 = (i + 1 < N) ? deg[i + 1] : 0;
    int v2 = (i + 2 < N) ? deg[i + 2] : 0;
    int v3 = (i + 3 < N) ? deg[i + 3] : 0;
    int tsum = v0 + v1 + v2 + v3;
    int xs = tsum;
    #pragma unroll
    for (int off = 1; off < 64; off <<= 1) {
        int y = __shfl_up(xs, off, 64);
        if (lane >= off) xs += y;
    }
    if (lane == 63) ws[wv] = xs;
    __syncthreads();
    int wprefix = 0;
    #pragma unroll
    for (int w2 = 0; w2 < 4; w2++) wprefix += (w2 < wv) ? ws[w2] : 0;
    int chunk_total = ws[0] + ws[1] + ws[2] + ws[3];

    if (wv == 0) {
        if (lane == 0)
            st_rel64(&lb[sb], ((u64)(unsigned)chunk_total << 2) | 1ull);
        int contrib = 0;
        if (sb > 0) {
            int pred = sb - 1 - lane;  // lane 0 = nearest predecessor
            for (;;) {
                u64 v = (pred >= 0) ? ld_acq64(&lb[pred]) : 2ull;  // sentinel: flag 2, val 0
                int flag = (int)(v & 3);
                u64 ball2 = __ballot(flag == 2);
                u64 ball0 = __ballot(flag == 0);
                if (ball2 != 0) {
                    int L = __ffsll(ball2) - 1;
                    if ((ball0 & ((1ull << L) - 1)) == 0) {
                        contrib = (lane <= L) ? (int)(unsigned)(v >> 2) : 0;
                        break;
                    }
                }
                __builtin_amdgcn_s_sleep(1);
            }
            #pragma unroll
            for (int off = 32; off >= 1; off >>= 1)
                contrib += __shfl_xor(contrib, off, 64);
        }
        if (lane == 0) {
            st_rel64(&lb[sb], ((u64)(unsigned)(contrib + chunk_total) << 2) | 2ull);
            s_prefix = contrib;
        }
    }
    __syncthreads();

    int carry = s_prefix;
    int e0 = carry + wprefix + xs - tsum;
    int e1 = e0 + v0, e2 = e1 + v1, e3 = e2 + v2;
    if (i + 0 < N) { offs[i + 0] = e0; dinv[i + 0] = rsqrtf((float)(v0 + 1)); }
    if (i + 1 < N) { offs[i + 1] = e1; dinv[i + 1] = rsqrtf((float)(v1 + 1)); }
    if (i + 2 < N) { offs[i + 2] = e2; dinv[i + 2] = rsqrtf((float)(v2 + 1)); }
    if (i + 3 < N) { offs[i + 3] = e3; dinv[i + 3] = rsqrtf((float)(v3 + 1)); }
    if (sb == SB - 1 && tid == 0) offs[N] = carry + chunk_total;
}

// ---------------------------------------------------------------------------
// fillgemm: blocks [0, FB) = CSR fill (no atomics: pos = offs[d] + rank[e]);
//           blocks [FB, FB+GB) = gemm1 with dinv-scaled epilogue.
// ---------------------------------------------------------------------------
__global__ __launch_bounds__(256) void fillgemm_kernel(
    const float* __restrict__ x, const unsigned short* __restrict__ W1f,
    unsigned short* __restrict__ h1, int N,
    const int* __restrict__ src, const int* __restrict__ dst, int E,
    const int* __restrict__ offs, const unsigned short* __restrict__ rank,
    const float* __restrict__ dinv, int* __restrict__ csr) {

    const int FB = (E + 255) / 256;
    int b = blockIdx.x;
    int tid = threadIdx.x;

    __shared__ unsigned short As[64 * 128];  // 16 KB (gemm blocks only)
    __shared__ float sdinv[64];

    if (b < FB) {
        int i = b * 256 + tid;
        if (i < E) {
            int s = src[i];
            int d = dst[i];
            int pos = offs[d] + (int)rank[i];
            csr[pos] = s;
        }
        return;
    }

    // ---------------- gemm1: h1 = dinv . (x @ W1) ----------------
    constexpr int K = 128, BN = 128;
    int lane = tid & 63;
    int w = tid >> 6;
    int row0 = (b - FB) * 64;

    if (tid < 64) {
        int gr = row0 + tid;
        sdinv[tid] = (gr < N) ? dinv[gr] : 0.f;
    }

    short8 bfr[2][4];
    #pragma unroll
    for (int nl = 0; nl < 2; nl++)
        #pragma unroll
        for (int ks = 0; ks < 4; ks++)
            bfr[nl][ks] = *(const short8*)(W1f + ((((w * 2 + nl) * 4 + ks) * 64) + lane) * 8);

    #pragma unroll
    for (int it = 0; it < 8; it++) {
        int idx = it * 256 + tid;
        int row = idx >> 5, kq = idx & 31;
        int k0 = kq * 4;
        int ks = k0 >> 5, quad = (k0 >> 3) & 3, j0 = k0 & 7, mt = row >> 4;
        ushort4 o = make_ushort4(0, 0, 0, 0);
        int gr = row0 + row;
        if (gr < N) {
            float4 a = *(const float4*)(x + (size_t)gr * K + k0);
            o.x = f2bf(a.x); o.y = f2bf(a.y); o.z = f2bf(a.z); o.w = f2bf(a.w);
        }
        int off = (((mt * 4 + ks) * 64) + (row & 15) + 16 * quad) * 8 + j0;
        *(ushort4*)(As + off) = o;
    }
    __syncthreads();

    f32x4 acc[4][2];
    #pragma unroll
    for (int mt = 0; mt < 4; mt++)
        #pragma unroll
        for (int nl = 0; nl < 2; nl++) acc[mt][nl] = (f32x4){0.f, 0.f, 0.f, 0.f};

    #pragma unroll
    for (int ks = 0; ks < 4; ks++) {
        short8 af[4];
        #pragma unroll
        for (int mt = 0; mt < 4; mt++)
            af[mt] = *(const short8*)(As + (((mt * 4 + ks) * 64) + lane) * 8);
        #pragma unroll
        for (int mt = 0; mt < 4; mt++)
            #pragma unroll
            for (int nl = 0; nl < 2; nl++)
                acc[mt][nl] = __builtin_amdgcn_mfma_f32_16x16x32_bf16(
                    af[mt], bfr[nl][ks], acc[mt][nl], 0, 0, 0);
    }

    int col16 = lane & 15;
    int rowq = lane >> 4;
    #pragma unroll
    for (int mt = 0; mt < 4; mt++) {
        #pragma unroll
        for (int nl = 0; nl < 2; nl++) {
            int gc = (w * 2 + nl) * 16 + col16;
            #pragma unroll
            for (int r = 0; r < 4; r++) {
                int lr = mt * 16 + rowq * 4 + r;
                int gr = row0 + lr;
                if (gr < N) h1[(size_t)gr * BN + gc] = f2bf(acc[mt][nl][r] * sdinv[lr]);
            }
        }
    }
}

// ---------------------------------------------------------------------------
// aggmm: fused Agg(layer1) + bias + ReLU + GEMM2, epilogue-scaled by dinv.
// Block = 4 waves = 16 nodes. 32 lanes/edge (uint2).
// R17: 4 nodes' streams interleaved BRANCHLESSLY -- per iter, 8 loads
// (4 nodes x 2 slot-unroll) issued straight-line with clamped shfl indices
// (dead slots = L1-hit re-read of last row, weight 0), then accumulates.
// ---------------------------------------------------------------------------
__global__ __launch_bounds__(256) void aggmm_kernel(const unsigned short* __restrict__ h1,
                                                    const int* __restrict__ offs,
                                                    const int* __restrict__ csr,
                                                    const float* __restrict__ dinv,
                                                    const float* __restrict__ b1,
                                                    const unsigned short* __restrict__ W2f,
                                                    unsigned short* __restrict__ h2,
                                                    int n) {
    __shared__ unsigned short As[4 * 64 * 8];  // 4 KB, one 16x128 A-tile

    int tid = threadIdx.x;
    int t = tid & 63;
    int w = tid >> 6;
    int p = t >> 5;      // edge slot (0/1)
    int t5 = t & 31;     // feature quad index (4 bf16)
    int nodebase = blockIdx.x * 16;
    int node0 = nodebase + w * 4;

    // preload offs[node0..node0+4], csr blocks (deg<=64), dinv per node
    int ov = offs[min(node0 + min(t, 4), n)];
    int e0a[4], dega[4], nba[4], cidx[4];
    float dia[4];
    #pragma unroll
    for (int i = 0; i < 4; i++) {
        e0a[i] = __shfl(ov, i, 64);
        dega[i] = __shfl(ov, i + 1, 64) - e0a[i];
        nba[i] = min(dega[i], 64);
        int ce = e0a[i] + min(t, max(dega[i] - 1, 0));
        cidx[i] = (dega[i] > 0) ? csr[ce] : 0;
        int node = node0 + i;
        dia[i] = (node < n) ? dinv[node] : 0.f;
    }

    short8 bw[4];
    #pragma unroll
    for (int ks = 0; ks < 4; ks++)
        bw[ks] = *(const short8*)(W2f + (((w * 4 + ks) * 64) + t) * 8);

    float4 bias = *(const float4*)(b1 + t5 * 4);

    float a[4][4];
    #pragma unroll
    for (int i = 0; i < 4; i++)
        #pragma unroll
        for (int k = 0; k < 4; k++) a[i][k] = 0.f;

    // self terms (p==0 slot; dinv folded into h1 rows already)
    #pragma unroll
    for (int i = 0; i < 4; i++) {
        int node = node0 + i;
        if (node < n && p == 0) {
            uint2 su = *(const uint2*)(h1 + (size_t)node * 128 + t5 * 4);
            a[i][0] = bf2f_lo(su.x); a[i][1] = bf2f_hi(su.x);
            a[i][2] = bf2f_lo(su.y); a[i][3] = bf2f_hi(su.y);
        }
    }

    // branchless interleaved main loop: granule 4/node (2 slots x unroll 2)
    int itTop = (max(max(nba[0], nba[1]), max(nba[2], nba[3])) + 3) >> 2;
    for (int it = 0; it < itTop; ++it) {
        int base = it * 4;
        uint2 hu[4][2];
        float wv[4][2];
        #pragma unroll
        for (int i = 0; i < 4; i++) {
            #pragma unroll
            for (int j = 0; j < 2; j++) {
                int ee = base + j * 2 + p;
                int ec = min(ee, nba[i] - 1);          // -1 only if deg==0 (cidx==0, safe)
                int s = __shfl(cidx[i], ec, 64);
                wv[i][j] = (ee < nba[i]) ? 1.f : 0.f;
                hu[i][j] = *(const uint2*)(h1 + (size_t)s * 128 + t5 * 4);
            }
        }
        #pragma unroll
        for (int i = 0; i < 4; i++)
            #pragma unroll
            for (int j = 0; j < 2; j++) {
                a[i][0] += bf2f_lo(hu[i][j].x) * wv[i][j];
                a[i][1] += bf2f_hi(hu[i][j].x) * wv[i][j];
                a[i][2] += bf2f_lo(hu[i][j].y) * wv[i][j];
                a[i][3] += bf2f_hi(hu[i][j].y) * wv[i][j];
            }
    }
    // rare tail: deg > 64
    #pragma unroll
    for (int i = 0; i < 4; i++) {
        int e1 = e0a[i] + dega[i];
        for (int eb = e0a[i] + 64; eb < e1; eb += 8) {
            #pragma unroll
            for (int j = 0; j < 4; j++) {
                int ee = eb + j * 2 + p;
                int ec = min(ee, e1 - 1);
                int s = csr[ec];
                float wgt = (ee < e1) ? 1.f : 0.f;
                uint2 hu = *(const uint2*)(h1 + (size_t)s * 128 + t5 * 4);
                a[i][0] += bf2f_lo(hu.x) * wgt; a[i][1] += bf2f_hi(hu.x) * wgt;
                a[i][2] += bf2f_lo(hu.y) * wgt; a[i][3] += bf2f_hi(hu.y) * wgt;
            }
        }
    }

    // reduce slots, bias+relu, stage into As
    #pragma unroll
    for (int i = 0; i < 4; i++) {
        float a0 = a[i][0], a1 = a[i][1], a2 = a[i][2], a3 = a[i][3];
        a0 += __shfl_xor(a0, 32, 64);
        a1 += __shfl_xor(a1, 32, 64);
        a2 += __shfl_xor(a2, 32, 64);
        a3 += __shfl_xor(a3, 32, 64);
        if (p == 0) {
            a0 = fmaxf(a0 * dia[i] + bias.x, 0.f);
            a1 = fmaxf(a1 * dia[i] + bias.y, 0.f);
            a2 = fmaxf(a2 * dia[i] + bias.z, 0.f);
            a3 = fmaxf(a3 * dia[i] + bias.w, 0.f);
            int row16 = w * 4 + i;
            int k0 = t5 * 4;
            int ks = k0 >> 5, quad = (k0 >> 3) & 3, j0 = k0 & 7;
            ushort4 pk4 = make_ushort4(f2bf(a0), f2bf(a1), f2bf(a2), f2bf(a3));
            *(ushort4*)(As + ((ks * 64) + row16 + 16 * quad) * 8 + j0) = pk4;
        }
    }
    __syncthreads();

    f32x4 acc = (f32x4){0.f, 0.f, 0.f, 0.f};
    #pragma unroll
    for (int ks = 0; ks < 4; ks++) {
        short8 af = *(const short8*)(As + ((ks * 64) + t) * 8);
        acc = __builtin_amdgcn_mfma_f32_16x16x32_bf16(af, bw[ks], acc, 0, 0, 0);
    }

    int col = w * 16 + (t & 15);
    int rowq = t >> 4;
    #pragma unroll
    for (int r = 0; r < 4; r++) {
        int gr = nodebase + rowq * 4 + r;
        if (gr < n) h2[(size_t)gr * 64 + col] = f2bf(acc[r] * dinv[gr]);
    }
}

// ---------------------------------------------------------------------------
// aggout: out[d] = dinv[d]*(h2'[d] + sum_e h2'[src]) + b2, fp32 out.
// R17: 4 nodes/wave, 16 lanes/edge, branchless interleave -- 8 loads
// (4 nodes x 2 unroll, 4 slots) straight-line, then accumulates.
// ---------------------------------------------------------------------------
__global__ __launch_bounds__(256) void aggout_kernel(const unsigned short* __restrict__ h2,
                                                     const int* __restrict__ offs,
                                                     const int* __restrict__ csr,
                                                     const float* __restrict__ dinv,
                                                     const float* __restrict__ b2,
                                                     float* __restrict__ out, int n) {
    int tid = threadIdx.x;
    int t = tid & 63;
    int w = tid >> 6;
    int p = t >> 4;      // edge slot (0..3)
    int t4 = t & 15;     // feature quad index
    int node0 = blockIdx.x * 16 + w * 4;

    int ov = offs[min(node0 + min(t, 4), n)];
    int e0a[4], dega[4], nba[4], cidx[4];
    float dia[4];
    #pragma unroll
    for (int i = 0; i < 4; i++) {
        e0a[i] = __shfl(ov, i, 64);
        dega[i] = __shfl(ov, i + 1, 64) - e0a[i];
        nba[i] = min(dega[i], 64);
        int ce = e0a[i] + min(t, max(dega[i] - 1, 0));
        cidx[i] = (dega[i] > 0) ? csr[ce] : 0;
        int node = node0 + i;
        dia[i] = (node < n) ? dinv[node] : 0.f;
    }

    float a[4][4];
    #pragma unroll
    for (int i = 0; i < 4; i++)
        #pragma unroll
        for (int k = 0; k < 4; k++) a[i][k] = 0.f;

    // self terms (p==0 slot)
    #pragma unroll
    for (int i = 0; i < 4; i++) {
        int node = node0 + i;
        if (node < n && p == 0) {
            uint2 su = *(const uint2*)(h2 + (size_t)node * 64 + t4 * 4);
            a[i][0] = bf2f_lo(su.x); a[i][1] = bf2f_hi(su.x);
            a[i][2] = bf2f_lo(su.y); a[i][3] = bf2f_hi(su.y);
        }
    }

    // branchless interleaved loop: granule 8/node (4 slots x unroll 2)
    int itTop = (max(max(nba[0], nba[1]), max(nba[2], nba[3])) + 7) >> 3;
    for (int it = 0; it < itTop; ++it) {
        int base = it * 8;
        uint2 hu[4][2];
        float wv[4][2];
        #pragma unroll
        for (int i = 0; i < 4; i++) {
            #pragma unroll
            for (int j = 0; j < 2; j++) {
                int ee = base + j * 4 + p;
                int ec = min(ee, nba[i] - 1);
                int s = __shfl(cidx[i], ec, 64);
                wv[i][j] = (ee < nba[i]) ? 1.f : 0.f;
                hu[i][j] = *(const uint2*)(h2 + (size_t)s * 64 + t4 * 4);
            }
        }
        #pragma unroll
        for (int i = 0; i < 4; i++)
            #pragma unroll
            for (int j = 0; j < 2; j++) {
                a[i][0] += bf2f_lo(hu[i][j].x) * wv[i][j];
                a[i][1] += bf2f_hi(hu[i][j].x) * wv[i][j];
                a[i][2] += bf2f_lo(hu[i][j].y) * wv[i][j];
                a[i][3] += bf2f_hi(hu[i][j].y) * wv[i][j];
            }
    }
    // rare tail: deg > 64
    #pragma unroll
    for (int i = 0; i < 4; i++) {
        int e1 = e0a[i] + dega[i];
        for (int eb = e0a[i] + 64; eb < e1; eb += 8) {
            #pragma unroll
            for (int j = 0; j < 2; j++) {
                int ee = eb + j * 4 + p;
                int ec = min(ee, e1 - 1);
                int s = csr[ec];
                float wgt = (ee < e1) ? 1.f : 0.f;
                uint2 hu = *(const uint2*)(h2 + (size_t)s * 64 + t4 * 4);
                a[i][0] += bf2f_lo(hu.x) * wgt; a[i][1] += bf2f_hi(hu.x) * wgt;
                a[i][2] += bf2f_lo(hu.y) * wgt; a[i][3] += bf2f_hi(hu.y) * wgt;
            }
        }
    }

    #pragma unroll
    for (int i = 0; i < 4; i++) {
        float a0 = a[i][0], a1 = a[i][1], a2 = a[i][2], a3 = a[i][3];
        a0 += __shfl_xor(a0, 16, 64); a1 += __shfl_xor(a1, 16, 64);
        a2 += __shfl_xor(a2, 16, 64); a3 += __shfl_xor(a3, 16, 64);
        a0 += __shfl_xor(a0, 32, 64); a1 += __shfl_xor(a1, 32, 64);
        a2 += __shfl_xor(a2, 32, 64); a3 += __shfl_xor(a3, 32, 64);
        int node = node0 + i;
        if (p == 0 && node < n) {
            float4 bb = *(const float4*)(b2 + t4 * 4);
            *(float4*)(out + (size_t)node * 64 + t4 * 4) =
                make_float4(a0 * dia[i] + bb.x, a1 * dia[i] + bb.y,
                            a2 * dia[i] + bb.z, a3 * dia[i] + bb.w);
        }
    }
}

extern "C" void kernel_launch(void* const* d_in, const int* in_sizes, int n_in,
                              void* d_out, int out_size, void* d_ws, size_t ws_size,
                              hipStream_t stream) {
    const float* x  = (const float*)d_in[0];
    const int*   ei = (const int*)d_in[1];
    const float* W1 = (const float*)d_in[2];
    const float* b1 = (const float*)d_in[3];
    const float* W2 = (const float*)d_in[4];
    const float* b2 = (const float*)d_in[5];

    const int N = in_sizes[0] / 128;   // 50000
    const int E = in_sizes[1] / 2;     // 500000
    const int* src = ei;
    const int* dst = ei + E;

    char* p = (char*)d_ws;
    auto alloc = [&](size_t bytes) {
        char* r = p;
        p += (bytes + 255) & ~(size_t)255;
        return r;
    };
    int*   degi  = (int*)  alloc((size_t)N * 4);
    float* dinv  = (float*)alloc((size_t)N * 4);
    int*   offs  = (int*)  alloc((size_t)(N + 1) * 4);
    u64*   lb    = (u64*)  alloc((size_t)64 * 8);
    unsigned short* rank = (unsigned short*)alloc((size_t)E * 2);
    int*            csr  = (int*)alloc((size_t)E * 4);
    unsigned short* W1f  = (unsigned short*)alloc((size_t)128 * 128 * 2);
    unsigned short* W2f  = (unsigned short*)alloc((size_t)64 * 128 * 2);
    unsigned short* h1   = (unsigned short*)alloc((size_t)N * 128 * 2);
    unsigned short* h2   = (unsigned short*)alloc((size_t)N * 64 * 2);
    float* out = (float*)d_out;

    const int GB = (N + 63) / 64;        // 782
    const int FB = (E + 255) / 256;      // 1954
    const int SB = (N + 1023) / 1024;    // 49
    const int CB = (E / 4 + 255) / 256;  // 489

    hipMemsetAsync(degi, 0, (size_t)N * 4, stream);
    count_kernel<<<CB + 12, 256, 0, stream>>>(dst, E, degi, rank,
                                              W1, W2, W1f, W2f, lb, CB);
    scan_lb_kernel<<<SB, 256, 0, stream>>>(degi, N, lb, offs, dinv);
    fillgemm_kernel<<<FB + GB, 256, 0, stream>>>(x, W1f, h1, N, src, dst, E,
                                                 offs, rank, dinv, csr);
    aggmm_kernel<<<(N + 15) / 16, 256, 0, stream>>>(h1, offs, csr, dinv, b1, W2f, h2, N);
    aggout_kernel<<<(N + 15) / 16, 256, 0, stream>>>(h2, offs, csr, dinv, b2, out, N);
}